// Round 6
// baseline (196.688 us; speedup 1.0000x reference)
//
#include <hip/hip_runtime.h>

// VariableLengthAttention: B=8, L=1024, H=16, D=64, fp32 in/out.
// R12: R8 (last passing kernel, 80.3us/dispatch) byte-identical EXCEPT
// ISSUE gains a SALU fast path for full tiles (delta (b) in isolation).
//   Bisect history: R9/R10/R11 all NaN'd; R11 proved the 32-key att[2]
//   control-flow rewrite (delta (a)) is the broken piece despite repeated
//   clean audits -- abandoned pending asm-level debugging. (b) is pure
//   address algebra on wave-uniform values:
//     full tile (kb+64 <= len): addr = readfirstlane((s0+kb)*3072+1024+h64)
//       + (krow*3072 + kd8)  [== clamped per-lane form, clamp unneeded]
//     V: readfirstlane((s0+kb+vk0)*3072+2048+h64) + lane, + (cc*4+t)*3072.
//   Tail tiles keep R8's per-lane clamped path (unused at len=1024).
// R8 design (unchanged):
//   - att[2] at 64-key granularity: QK(kt) + PV(kt-1) in one MFMA region;
//     exp/pack(kt) after, overlapped by PV issue. paf[4] carries P frags.
//   - V triple-buffered, K double-buffered in LDS (47KB, 2 blocks/CU).
//   - one raw barrier per kt (lgkmcnt(0)+s_barrier; vmcnt stays in flight).
//   - 32x32x16 bf16 MFMA, swapped QK^T, in-register softmax via cvt_pk +
//     v_permlane32_swap, l via VALU adds + shfl_xor + LDS transpose,
//     fixed max=0, Q pre-scaled by 0.125*log2(e).

typedef __attribute__((ext_vector_type(4))) float f32x4;
typedef __attribute__((ext_vector_type(16))) float f32x16;
typedef __attribute__((ext_vector_type(8))) __bf16 bf16x8;
typedef __attribute__((ext_vector_type(8))) unsigned short us8;

#if __has_builtin(__builtin_amdgcn_exp2f)
#define EXP2F __builtin_amdgcn_exp2f
#else
#define EXP2F exp2f
#endif
#if __has_builtin(__builtin_amdgcn_rcpf)
#define RCPF __builtin_amdgcn_rcpf
#else
#define RCPF(x) (1.0f / (x))
#endif

__device__ __forceinline__ unsigned pk_bf16(float a, float b) {
#if __has_builtin(__builtin_amdgcn_cvt_pk_bf16_f32)
  auto r = __builtin_amdgcn_cvt_pk_bf16_f32(a, b);
  return __builtin_bit_cast(unsigned, r);
#else
  unsigned ra = __builtin_bit_cast(unsigned, a) + 0x8000u;
  unsigned rb = __builtin_bit_cast(unsigned, b) + 0x8000u;
  return __builtin_amdgcn_perm(rb, ra, 0x07060302u);
#endif
}

#define KSTR 72                              // ushorts/row: 64 data + 8 pad
#define KBUF(b) ((b) * (64 * KSTR))          // K buffers: b in {0,1}
#define VBUF(b) ((2 + (b)) * (64 * KSTR))    // V buffers: b in {0,1,2}
#define SMEM_US (5 * 64 * KSTR)              // 23040 us = 46080 B

// raw barrier: LDS drained, global loads stay in flight
#define BAR() asm volatile("s_waitcnt lgkmcnt(0)\n\ts_barrier" ::: "memory")

#define ZERO16(X)                                                             \
  _Pragma("unroll") for (int z_ = 0; z_ < 16; ++z_) (X)[z_] = 0.f

// issue global loads for K/V tile T into registers (k0,k1,vv)
// Full tiles: SALU base via readfirstlane + thread-invariant voffset.
// Tail tiles: R8's per-lane clamped path.
#define ISSUE(T)                                                              \
  do {                                                                        \
    const int kb_ = (T) * 64;                                                 \
    if (kb_ + 64 <= len) {                                                    \
      const int kbs_ =                                                        \
          __builtin_amdgcn_readfirstlane((s0 + kb_) * 3072 + 1024 + h64);     \
      const float* kp_ = qkv + kbs_ + kvo;                                    \
      k0 = *(const float4*)kp_;                                               \
      k1 = *(const float4*)(kp_ + 4);                                         \
      const int vbs_ = __builtin_amdgcn_readfirstlane(                        \
          (s0 + kb_ + vk0) * 3072 + 2048 + h64);                              \
      const float* vp_ = qkv + vbs_ + lane;                                   \
      _Pragma("unroll") for (int cc_ = 0; cc_ < 2; ++cc_)                     \
          _Pragma("unroll") for (int t_ = 0; t_ < 4; ++t_)                    \
              vv[cc_][t_] = vp_[(cc_ * 4 + t_) * 3072];                       \
    } else {                                                                  \
      int kt_ = s0 + kb_ + krow;                                              \
      kt_ = kt_ > tmax ? tmax : kt_;                                          \
      const float* kp_ = qkv + (size_t)kt_ * 3072 + 1024 + h64 + kd8;         \
      k0 = *(const float4*)kp_;                                               \
      k1 = *(const float4*)(kp_ + 4);                                         \
      _Pragma("unroll") for (int cc_ = 0; cc_ < 2; ++cc_) {                   \
        _Pragma("unroll") for (int t_ = 0; t_ < 4; ++t_) {                    \
          int vt_ = s0 + kb_ + vk0 + cc_ * 4 + t_;                            \
          vt_ = vt_ > tmax ? tmax : vt_;                                      \
          vv[cc_][t_] = qkv[(size_t)vt_ * 3072 + 2048 + h64 + lane];          \
        }                                                                     \
      }                                                                       \
    }                                                                         \
  } while (0)

// convert + commit staged registers into K[(T)&1] / VT[(T)%3]  (R8-verbatim)
#define COMMIT(T)                                                             \
  do {                                                                        \
    const int kbi_ = (T) & 1, vbi_ = (T) % 3;                                 \
    uint4 kw_ = {pk_bf16(k0.x, k0.y), pk_bf16(k0.z, k0.w),                    \
                 pk_bf16(k1.x, k1.y), pk_bf16(k1.z, k1.w)};                   \
    *(uint4*)&smem[KBUF(kbi_) + krow * KSTR + kd8] = kw_;                     \
    _Pragma("unroll") for (int cc_ = 0; cc_ < 2; ++cc_) {                     \
      uint2 vw_ = {pk_bf16(vv[cc_][0], vv[cc_][1]),                           \
                   pk_bf16(vv[cc_][2], vv[cc_][3])};                          \
      *(uint2*)&smem[VBUF(vbi_) + lane * KSTR + vk0 + cc_ * 4] = vw_;         \
    }                                                                         \
  } while (0)

// S^T += K(32-key tile TT of buffer KB) * Q  (R8-verbatim)
#define QKT(SREG, TT, KB)                                                     \
  do {                                                                        \
    const int krd_ = KBUF(KB) + ((TT) * 32 + q5) * KSTR + hi * 8;             \
    _Pragma("unroll") for (int ks_ = 0; ks_ < 4; ++ks_) {                     \
      bf16x8 kf_ =                                                            \
          __builtin_bit_cast(bf16x8, *(const us8*)&smem[krd_ + ks_ * 16]);    \
      SREG = __builtin_amdgcn_mfma_f32_32x32x16_bf16(kf_, qf[ks_], SREG, 0,   \
                                                     0, 0);                   \
    }                                                                         \
  } while (0)

// mask(partial) + exp2 + l-accum + pack -> paf[TT*2], paf[TT*2+1] (R8-verbatim)
#define EXPPACK(SREG, TT)                                                     \
  do {                                                                        \
    if (partial) {                                                            \
      _Pragma("unroll") for (int r_ = 0; r_ < 16; ++r_) {                     \
        const int key_ = (TT) * 32 + (r_ & 3) + ((r_ >> 2) << 3) + hi * 4;    \
        if (kbase + key_ >= len) SREG[r_] = -1e30f;                           \
      }                                                                       \
    }                                                                         \
    float p_[16];                                                             \
    _Pragma("unroll") for (int r_ = 0; r_ < 16; ++r_) p_[r_] = EXP2F(SREG[r_]); \
    _Pragma("unroll") for (int r_ = 0; r_ < 16; ++r_) lacc[r_ & 3] += p_[r_]; \
    _Pragma("unroll") for (int m_ = 0; m_ < 2; ++m_) {                        \
      unsigned w0_ = pk_bf16(p_[m_ * 8 + 0], p_[m_ * 8 + 1]);                 \
      unsigned w1_ = pk_bf16(p_[m_ * 8 + 2], p_[m_ * 8 + 3]);                 \
      unsigned w2_ = pk_bf16(p_[m_ * 8 + 4], p_[m_ * 8 + 5]);                 \
      unsigned w3_ = pk_bf16(p_[m_ * 8 + 6], p_[m_ * 8 + 7]);                 \
      asm("v_permlane32_swap_b32 %0, %1" : "+v"(w0_), "+v"(w2_));             \
      asm("v_permlane32_swap_b32 %0, %1" : "+v"(w1_), "+v"(w3_));             \
      uint4 fw_ = {w0_, w1_, w2_, w3_};                                       \
      paf[(TT) * 2 + m_] = __builtin_bit_cast(bf16x8, fw_);                   \
    }                                                                         \
  } while (0)

// O += P(prev tile) * V from VT buffer VB  (R8-verbatim)
#define PV(VB)                                                                \
  do {                                                                        \
    _Pragma("unroll") for (int dt_ = 0; dt_ < 2; ++dt_) {                     \
      const int vrd_ = VBUF(VB) + (dt_ * 32 + q5) * KSTR + hi * 8;            \
      _Pragma("unroll") for (int kc_ = 0; kc_ < 4; ++kc_) {                   \
        bf16x8 vf_ =                                                          \
            __builtin_bit_cast(bf16x8, *(const us8*)&smem[vrd_ + kc_ * 16]);  \
        Oc[dt_] = __builtin_amdgcn_mfma_f32_32x32x16_bf16(paf[kc_], vf_,      \
                                                          Oc[dt_], 0, 0, 0); \
      }                                                                       \
    }                                                                         \
  } while (0)

__launch_bounds__(512, 4)
__global__ void vla_fa_kernel(const float* __restrict__ qkv,
                              const int* __restrict__ cu,
                              float* __restrict__ out,
                              int B, int nflat) {
  __shared__ __align__(16) unsigned short smem[SMEM_US];
  __shared__ __align__(16) float ldsL[256];
  const int tid = threadIdx.x;
  const int wave = tid >> 6, lane = tid & 63;
  const int q5 = lane & 31, hi = lane >> 5;        // C col / k-chunk half
  const int krow = tid >> 3, kd8 = (tid & 7) * 8;  // K staging: half-row/thread
  const int kvo = krow * 3072 + kd8;               // invariant K voffset
  const int vk0 = wave * 8;                        // V staging key base
  const int BH = B * 16;

  for (int flat = blockIdx.x; flat < nflat; flat += gridDim.x) {
    const int b = flat % B;
    const int h = (flat / B) & 15;
    const int qb = flat / BH;                      // qb slowest
    const int s0 = cu[b], s1 = cu[b + 1];
    const int len = s1 - s0;
    if (qb * 256 >= len) continue;                 // block-uniform
    const int tmax = s1 - 1;
    const int h64 = h * 64;
    const int nkt = (len + 63) >> 6;

    float4 k0, k1;
    float vv[2][4];
    ISSUE(0);                                      // tile-0 loads first in queue

    // ---- Q fragments direct from global (pre-scaled by 0.125*log2e) ----
    const float fs = 0.18033688011112042f;
    int qtok = s0 + qb * 256 + wave * 32 + q5;
    qtok = qtok > tmax ? tmax : qtok;
    const float* qp = qkv + (size_t)qtok * 3072 + h64 + hi * 8;
    bf16x8 qf[4];
#pragma unroll
    for (int ks = 0; ks < 4; ++ks) {
      float4 a = *(const float4*)(qp + ks * 16);
      float4 c = *(const float4*)(qp + ks * 16 + 4);
      uint4 w = {pk_bf16(a.x * fs, a.y * fs), pk_bf16(a.z * fs, a.w * fs),
                 pk_bf16(c.x * fs, c.y * fs), pk_bf16(c.z * fs, c.w * fs)};
      qf[ks] = __builtin_bit_cast(bf16x8, w);
    }

    f32x16 Oc[2];
    ZERO16(Oc[0]);
    ZERO16(Oc[1]);
    float lacc[4] = {0.f, 0.f, 0.f, 0.f};
    bf16x8 paf[4];

    BAR();                                         // prior item's LDS reads done
    COMMIT(0);
    if (nkt > 1) ISSUE(1);
    BAR();                                         // K[0], VT[0] visible

    // ---- peeled kt = 0: QK + exp/pack only (no PV yet) ----
    {
      const int kbase = 0;
      const bool partial = len < 64;
      f32x16 S0, S1;
      ZERO16(S0);
      ZERO16(S1);
      __builtin_amdgcn_s_setprio(1);
      QKT(S0, 0, 0);
      QKT(S1, 1, 0);
      __builtin_amdgcn_s_setprio(0);
      if (nkt > 1) COMMIT(1);
      if (nkt > 2) ISSUE(2);
      EXPPACK(S0, 0);
      EXPPACK(S1, 1);
      BAR();
    }

    // ---- main loop: QK(kt) || PV(kt-1) merged, exp/pack(kt) after ----
    for (int kt = 1; kt < nkt; ++kt) {
      const int kbase = kt * 64;
      const bool partial = (len - kbase) < 64;
      const int kb = kt & 1;
      const int vbPrev = (kt - 1) % 3;
      f32x16 S0, S1;
      ZERO16(S0);
      ZERO16(S1);

      __builtin_amdgcn_s_setprio(1);
      QKT(S0, 0, kb);
      QKT(S1, 1, kb);
      PV(vbPrev);                    // reads paf BEFORE pack overwrites it
      __builtin_amdgcn_s_setprio(0);

      if (kt + 1 < nkt) COMMIT(kt + 1);
      if (kt + 2 < nkt) ISSUE(kt + 2);

      EXPPACK(S0, 0);                // exp waits QK retire; PV issue covers it
      EXPPACK(S1, 1);
      BAR();
    }

    // ---- tail: PV of the last tile ----
    __builtin_amdgcn_s_setprio(1);
    PV((nkt - 1) % 3);
    __builtin_amdgcn_s_setprio(0);

    // ---- epilogue: l transpose (wave-private) and out = O / l ----
    float lt = (lacc[0] + lacc[1]) + (lacc[2] + lacc[3]);
    lt += __shfl_xor(lt, 32, 64);                  // other key half
    if (hi == 0) ldsL[wave * 32 + q5] = lt;
    asm volatile("s_waitcnt lgkmcnt(0)" ::: "memory");
    const int rbase = qb * 256 + wave * 32;
#pragma unroll
    for (int g = 0; g < 4; ++g) {
      f32x4 lv = *(const f32x4*)&ldsL[wave * 32 + g * 8 + hi * 4];
#pragma unroll
      for (int j = 0; j < 4; ++j) {
        const int r = g * 4 + j;                   // C row = j + 8g + 4hi
        const int row = rbase + g * 8 + hi * 4 + j;
        if (row < len) {
          const float rl = RCPF(lv[j]);
          float* op = out + (size_t)(s0 + row) * 1024 + h64 + q5;
          op[0] = Oc[0][r] * rl;
          op[32] = Oc[1][r] * rl;
        }
      }
    }
  }
}

extern "C" void kernel_launch(void* const* d_in, const int* in_sizes, int n_in,
                              void* d_out, int out_size, void* d_ws, size_t ws_size,
                              hipStream_t stream) {
  const float* qkv = (const float*)d_in[0];
  const int* cu = (const int*)d_in[1];
  float* out = (float*)d_out;
  int B = in_sizes[1] - 1;                         // 8
  int total_N = in_sizes[0] / (3 * 16 * 64);       // 8192
  int qbmax = (total_N + 255) / 256;               // covers any single seq
  int nflat = B * 16 * qbmax;
  int nb = nflat < 512 ? nflat : 512;              // 2 blocks/CU, one generation
  dim3 grid(nb), block(512, 1, 1);
  hipLaunchKernelGGL(vla_fa_kernel, grid, block, 0, stream, qkv, cu, out, B, nflat);
}

// Round 8
// 189.518 us; speedup vs baseline: 1.0378x; 1.0378x over previous
//
#include <hip/hip_runtime.h>

// VariableLengthAttention: B=8, L=1024, H=16, D=64, fp32 in/out.
// R14 = R13 resubmitted verbatim (R13's bench run died to a container
// acquisition failure -- "MI355X container failed twice" -- so it never
// touched hardware; no evidence to act on).
// R13 = R8 (last fast passing kernel, 80.3us/dispatch) with:
//   1. ISSUE reverted to R8's per-lane clamped addressing.
//      (R12 measured: readfirstlane SALU addressing = +10us stall despite
//       -5us VALU — scalar-base chains serialize against load issue.)
//   2. in-loop s_setprio pair REMOVED. The builtins are scheduling fences
//      around the MFMA region; without them the compiler may interleave
//      COMMIT's cvt_pk/ds_writes and EXPPACK's exp2 chain into the 24-MFMA
//      issue window (VALU and MFMA co-issue on separate pipes, m114).
//      Evidence: R6 (no setprio) fastest; R7 (dense setprio) slowest.
// R8 design (unchanged):
//   - att[2] at 64-key granularity: QK(kt) + PV(kt-1) in one MFMA region;
//     exp/pack(kt) after; PV consumes paf from the PREVIOUS iteration
//     (anti-dependency; pack overwrites only after PV read).
//   - V triple-buffered, K double-buffered in LDS (47KB, 2 blocks/CU).
//   - one raw barrier per kt (lgkmcnt(0)+s_barrier; vmcnt stays in flight).
//   - 32x32x16 bf16 MFMA, swapped QK^T (S^T = mfma(K,Q)), in-register
//     softmax via cvt_pk + v_permlane32_swap, l via VALU adds + shfl_xor +
//     LDS transpose, fixed max=0, Q pre-scaled by 0.125*log2(e).
// Bisect history: R9/R10/R11 (32-key cross-barrier S-carry) NaN'd and are
// abandoned; R12 (SALU addressing) measured slower and is reverted.

typedef __attribute__((ext_vector_type(4))) float f32x4;
typedef __attribute__((ext_vector_type(16))) float f32x16;
typedef __attribute__((ext_vector_type(8))) __bf16 bf16x8;
typedef __attribute__((ext_vector_type(8))) unsigned short us8;

#if __has_builtin(__builtin_amdgcn_exp2f)
#define EXP2F __builtin_amdgcn_exp2f
#else
#define EXP2F exp2f
#endif
#if __has_builtin(__builtin_amdgcn_rcpf)
#define RCPF __builtin_amdgcn_rcpf
#else
#define RCPF(x) (1.0f / (x))
#endif

__device__ __forceinline__ unsigned pk_bf16(float a, float b) {
#if __has_builtin(__builtin_amdgcn_cvt_pk_bf16_f32)
  auto r = __builtin_amdgcn_cvt_pk_bf16_f32(a, b);
  return __builtin_bit_cast(unsigned, r);
#else
  unsigned ra = __builtin_bit_cast(unsigned, a) + 0x8000u;
  unsigned rb = __builtin_bit_cast(unsigned, b) + 0x8000u;
  return __builtin_amdgcn_perm(rb, ra, 0x07060302u);
#endif
}

#define KSTR 72                              // ushorts/row: 64 data + 8 pad
#define KBUF(b) ((b) * (64 * KSTR))          // K buffers: b in {0,1}
#define VBUF(b) ((2 + (b)) * (64 * KSTR))    // V buffers: b in {0,1,2}
#define SMEM_US (5 * 64 * KSTR)              // 23040 us = 46080 B

// raw barrier: LDS drained, global loads stay in flight
#define BAR() asm volatile("s_waitcnt lgkmcnt(0)\n\ts_barrier" ::: "memory")

#define ZERO16(X)                                                             \
  _Pragma("unroll") for (int z_ = 0; z_ < 16; ++z_) (X)[z_] = 0.f

// issue global loads for K/V tile T into registers (k0,k1,vv) — R8-verbatim
#define ISSUE(T)                                                              \
  do {                                                                        \
    const int kb_ = (T) * 64;                                                 \
    int kt_ = s0 + kb_ + krow;                                                \
    kt_ = kt_ > tmax ? tmax : kt_;                                            \
    const float* kp_ = qkv + (size_t)kt_ * 3072 + 1024 + h64 + kd8;           \
    k0 = *(const float4*)kp_;                                                 \
    k1 = *(const float4*)(kp_ + 4);                                           \
    _Pragma("unroll") for (int cc_ = 0; cc_ < 2; ++cc_) {                     \
      _Pragma("unroll") for (int t_ = 0; t_ < 4; ++t_) {                      \
        int vt_ = s0 + kb_ + vk0 + cc_ * 4 + t_;                              \
        vt_ = vt_ > tmax ? tmax : vt_;                                        \
        vv[cc_][t_] = qkv[(size_t)vt_ * 3072 + 2048 + h64 + lane];            \
      }                                                                       \
    }                                                                         \
  } while (0)

// convert + commit staged registers into K[(T)&1] / VT[(T)%3]  (R8-verbatim)
#define COMMIT(T)                                                             \
  do {                                                                        \
    const int kbi_ = (T) & 1, vbi_ = (T) % 3;                                 \
    uint4 kw_ = {pk_bf16(k0.x, k0.y), pk_bf16(k0.z, k0.w),                    \
                 pk_bf16(k1.x, k1.y), pk_bf16(k1.z, k1.w)};                   \
    *(uint4*)&smem[KBUF(kbi_) + krow * KSTR + kd8] = kw_;                     \
    _Pragma("unroll") for (int cc_ = 0; cc_ < 2; ++cc_) {                     \
      uint2 vw_ = {pk_bf16(vv[cc_][0], vv[cc_][1]),                           \
                   pk_bf16(vv[cc_][2], vv[cc_][3])};                          \
      *(uint2*)&smem[VBUF(vbi_) + lane * KSTR + vk0 + cc_ * 4] = vw_;         \
    }                                                                         \
  } while (0)

// S^T += K(32-key tile TT of buffer KB) * Q  (R8-verbatim)
#define QKT(SREG, TT, KB)                                                     \
  do {                                                                        \
    const int krd_ = KBUF(KB) + ((TT) * 32 + q5) * KSTR + hi * 8;             \
    _Pragma("unroll") for (int ks_ = 0; ks_ < 4; ++ks_) {                     \
      bf16x8 kf_ =                                                            \
          __builtin_bit_cast(bf16x8, *(const us8*)&smem[krd_ + ks_ * 16]);    \
      SREG = __builtin_amdgcn_mfma_f32_32x32x16_bf16(kf_, qf[ks_], SREG, 0,   \
                                                     0, 0);                   \
    }                                                                         \
  } while (0)

// mask(partial) + exp2 + l-accum + pack -> paf[TT*2], paf[TT*2+1] (R8-verbatim)
#define EXPPACK(SREG, TT)                                                     \
  do {                                                                        \
    if (partial) {                                                            \
      _Pragma("unroll") for (int r_ = 0; r_ < 16; ++r_) {                     \
        const int key_ = (TT) * 32 + (r_ & 3) + ((r_ >> 2) << 3) + hi * 4;    \
        if (kbase + key_ >= len) SREG[r_] = -1e30f;                           \
      }                                                                       \
    }                                                                         \
    float p_[16];                                                             \
    _Pragma("unroll") for (int r_ = 0; r_ < 16; ++r_) p_[r_] = EXP2F(SREG[r_]); \
    _Pragma("unroll") for (int r_ = 0; r_ < 16; ++r_) lacc[r_ & 3] += p_[r_]; \
    _Pragma("unroll") for (int m_ = 0; m_ < 2; ++m_) {                        \
      unsigned w0_ = pk_bf16(p_[m_ * 8 + 0], p_[m_ * 8 + 1]);                 \
      unsigned w1_ = pk_bf16(p_[m_ * 8 + 2], p_[m_ * 8 + 3]);                 \
      unsigned w2_ = pk_bf16(p_[m_ * 8 + 4], p_[m_ * 8 + 5]);                 \
      unsigned w3_ = pk_bf16(p_[m_ * 8 + 6], p_[m_ * 8 + 7]);                 \
      asm("v_permlane32_swap_b32 %0, %1" : "+v"(w0_), "+v"(w2_));             \
      asm("v_permlane32_swap_b32 %0, %1" : "+v"(w1_), "+v"(w3_));             \
      uint4 fw_ = {w0_, w1_, w2_, w3_};                                       \
      paf[(TT) * 2 + m_] = __builtin_bit_cast(bf16x8, fw_);                   \
    }                                                                         \
  } while (0)

// O += P(prev tile) * V from VT buffer VB  (R8-verbatim)
#define PV(VB)                                                                \
  do {                                                                        \
    _Pragma("unroll") for (int dt_ = 0; dt_ < 2; ++dt_) {                     \
      const int vrd_ = VBUF(VB) + (dt_ * 32 + q5) * KSTR + hi * 8;            \
      _Pragma("unroll") for (int kc_ = 0; kc_ < 4; ++kc_) {                   \
        bf16x8 vf_ =                                                          \
            __builtin_bit_cast(bf16x8, *(const us8*)&smem[vrd_ + kc_ * 16]);  \
        Oc[dt_] = __builtin_amdgcn_mfma_f32_32x32x16_bf16(paf[kc_], vf_,      \
                                                          Oc[dt_], 0, 0, 0); \
      }                                                                       \
    }                                                                         \
  } while (0)

__launch_bounds__(512, 4)
__global__ void vla_fa_kernel(const float* __restrict__ qkv,
                              const int* __restrict__ cu,
                              float* __restrict__ out,
                              int B, int nflat) {
  __shared__ __align__(16) unsigned short smem[SMEM_US];
  __shared__ __align__(16) float ldsL[256];
  const int tid = threadIdx.x;
  const int wave = tid >> 6, lane = tid & 63;
  const int q5 = lane & 31, hi = lane >> 5;        // C col / k-chunk half
  const int krow = tid >> 3, kd8 = (tid & 7) * 8;  // K staging: half-row/thread
  const int vk0 = wave * 8;                        // V staging key base
  const int BH = B * 16;

  for (int flat = blockIdx.x; flat < nflat; flat += gridDim.x) {
    const int b = flat % B;
    const int h = (flat / B) & 15;
    const int qb = flat / BH;                      // qb slowest
    const int s0 = cu[b], s1 = cu[b + 1];
    const int len = s1 - s0;
    if (qb * 256 >= len) continue;                 // block-uniform
    const int tmax = s1 - 1;
    const int h64 = h * 64;
    const int nkt = (len + 63) >> 6;

    float4 k0, k1;
    float vv[2][4];
    ISSUE(0);                                      // tile-0 loads first in queue

    // ---- Q fragments direct from global (pre-scaled by 0.125*log2e) ----
    const float fs = 0.18033688011112042f;
    int qtok = s0 + qb * 256 + wave * 32 + q5;
    qtok = qtok > tmax ? tmax : qtok;
    const float* qp = qkv + (size_t)qtok * 3072 + h64 + hi * 8;
    bf16x8 qf[4];
#pragma unroll
    for (int ks = 0; ks < 4; ++ks) {
      float4 a = *(const float4*)(qp + ks * 16);
      float4 c = *(const float4*)(qp + ks * 16 + 4);
      uint4 w = {pk_bf16(a.x * fs, a.y * fs), pk_bf16(a.z * fs, a.w * fs),
                 pk_bf16(c.x * fs, c.y * fs), pk_bf16(c.z * fs, c.w * fs)};
      qf[ks] = __builtin_bit_cast(bf16x8, w);
    }

    f32x16 Oc[2];
    ZERO16(Oc[0]);
    ZERO16(Oc[1]);
    float lacc[4] = {0.f, 0.f, 0.f, 0.f};
    bf16x8 paf[4];

    BAR();                                         // prior item's LDS reads done
    COMMIT(0);
    if (nkt > 1) ISSUE(1);
    BAR();                                         // K[0], VT[0] visible

    // ---- peeled kt = 0: QK + exp/pack only (no PV yet) ----
    {
      const int kbase = 0;
      const bool partial = len < 64;
      f32x16 S0, S1;
      ZERO16(S0);
      ZERO16(S1);
      QKT(S0, 0, 0);
      QKT(S1, 1, 0);
      if (nkt > 1) COMMIT(1);
      if (nkt > 2) ISSUE(2);
      EXPPACK(S0, 0);
      EXPPACK(S1, 1);
      BAR();
    }

    // ---- main loop: QK(kt) || PV(kt-1) merged, exp/pack(kt) after ----
    for (int kt = 1; kt < nkt; ++kt) {
      const int kbase = kt * 64;
      const bool partial = (len - kbase) < 64;
      const int kb = kt & 1;
      const int vbPrev = (kt - 1) % 3;
      f32x16 S0, S1;
      ZERO16(S0);
      ZERO16(S1);

      QKT(S0, 0, kb);
      QKT(S1, 1, kb);
      PV(vbPrev);                    // reads paf BEFORE pack overwrites it

      if (kt + 1 < nkt) COMMIT(kt + 1);
      if (kt + 2 < nkt) ISSUE(kt + 2);

      EXPPACK(S0, 0);                // exp waits QK retire; PV issue covers it
      EXPPACK(S1, 1);
      BAR();
    }

    // ---- tail: PV of the last tile ----
    PV((nkt - 1) % 3);

    // ---- epilogue: l transpose (wave-private) and out = O / l ----
    float lt = (lacc[0] + lacc[1]) + (lacc[2] + lacc[3]);
    lt += __shfl_xor(lt, 32, 64);                  // other key half
    if (hi == 0) ldsL[wave * 32 + q5] = lt;
    asm volatile("s_waitcnt lgkmcnt(0)" ::: "memory");
    const int rbase = qb * 256 + wave * 32;
#pragma unroll
    for (int g = 0; g < 4; ++g) {
      f32x4 lv = *(const f32x4*)&ldsL[wave * 32 + g * 8 + hi * 4];
#pragma unroll
      for (int j = 0; j < 4; ++j) {
        const int r = g * 4 + j;                   // C row = j + 8g + 4hi
        const int row = rbase + g * 8 + hi * 4 + j;
        if (row < len) {
          const float rl = RCPF(lv[j]);
          float* op = out + (size_t)(s0 + row) * 1024 + h64 + q5;
          op[0] = Oc[0][r] * rl;
          op[32] = Oc[1][r] * rl;
        }
      }
    }
  }
}

extern "C" void kernel_launch(void* const* d_in, const int* in_sizes, int n_in,
                              void* d_out, int out_size, void* d_ws, size_t ws_size,
                              hipStream_t stream) {
  const float* qkv = (const float*)d_in[0];
  const int* cu = (const int*)d_in[1];
  float* out = (float*)d_out;
  int B = in_sizes[1] - 1;                         // 8
  int total_N = in_sizes[0] / (3 * 16 * 64);       // 8192
  int qbmax = (total_N + 255) / 256;               // covers any single seq
  int nflat = B * 16 * qbmax;
  int nb = nflat < 512 ? nflat : 512;              // 2 blocks/CU, one generation
  dim3 grid(nb), block(512, 1, 1);
  hipLaunchKernelGGL(vla_fa_kernel, grid, block, 0, stream, qkv, cu, out, B, nflat);
}